// Round 2
// baseline (781.783 us; speedup 1.0000x reference)
//
#include <hip/hip_runtime.h>

typedef unsigned short ushort_t;
typedef unsigned int uint_t;

typedef __bf16 bf16x8 __attribute__((ext_vector_type(8)));
typedef float f32x4 __attribute__((ext_vector_type(4)));
typedef uint_t uint32x4 __attribute__((ext_vector_type(4)));

// ---------- bf16 helpers (RNE fp32->bf16; bit-shift bf16->fp32) ----------
__device__ __forceinline__ float b2f(ushort_t u) {
    union { uint_t ui; float f; } c; c.ui = ((uint_t)u) << 16; return c.f;
}
__device__ __forceinline__ ushort_t f2b(float f) {
    union { float f; uint_t ui; } c; c.f = f;
    uint_t u = c.ui;
    uint_t r = (u + 0x7fffu + ((u >> 16) & 1u)) >> 16;
    return (ushort_t)r;
}
__device__ __forceinline__ float lo2f(uint_t v) {
    union { uint_t u; float f; } c; c.u = v << 16; return c.f;
}
__device__ __forceinline__ float hi2f(uint_t v) {
    union { uint_t u; float f; } c; c.u = v & 0xffff0000u; return c.f;
}

// ---------- fp32 -> bf16 cast (8 elems/thread) ----------
__global__ __launch_bounds__(256) void cast_kernel(const float* __restrict__ src,
                                                   ushort_t* __restrict__ dst, int n8) {
    int i = blockIdx.x * 256 + threadIdx.x;
    if (i >= n8) return;
    const f32x4* s = (const f32x4*)(src + (size_t)i * 8);
    f32x4 a = s[0], b = s[1];
    ushort_t o[8];
    o[0] = f2b(a[0]); o[1] = f2b(a[1]); o[2] = f2b(a[2]); o[3] = f2b(a[3]);
    o[4] = f2b(b[0]); o[5] = f2b(b[1]); o[6] = f2b(b[2]); o[7] = f2b(b[3]);
    *(uint32x4*)(dst + (size_t)i * 8) = *(uint32x4*)o;
}

// ---------- degree count ----------
__global__ __launch_bounds__(256) void count_kernel(const int* __restrict__ dst,
                                                    int* __restrict__ cnt, int E) {
    int e = blockIdx.x * 256 + threadIdx.x;
    if (e < E) atomicAdd(&cnt[dst[e]], 1);
}

// ---------- dinv = rsqrt(indeg + 1)  (self-loop always present -> deg>0) ----------
__global__ __launch_bounds__(256) void dinv_kernel(const int* __restrict__ cnt,
                                                   float* __restrict__ dinv, int n) {
    int i = blockIdx.x * 256 + threadIdx.x;
    if (i < n) dinv[i] = rsqrtf((float)(cnt[i] + 1));
}

// ---------- scan pass 1: per-block sums ----------
__global__ __launch_bounds__(256) void reduce256(const int* __restrict__ cnt,
                                                 int* __restrict__ bsums, int n) {
    __shared__ int s[256];
    int t = threadIdx.x, g = blockIdx.x * 256 + t;
    s[t] = (g < n) ? cnt[g] : 0;
    __syncthreads();
    for (int o = 128; o > 0; o >>= 1) {
        if (t < o) s[t] += s[t + o];
        __syncthreads();
    }
    if (t == 0) bsums[blockIdx.x] = s[0];
}

// ---------- scan pass 2: exclusive scan of block sums (single block) ----------
__global__ __launch_bounds__(512) void scan_block(const int* __restrict__ bsums,
                                                  int* __restrict__ boffs, int nb,
                                                  int* __restrict__ offs, int N, int E) {
    __shared__ int s[512];
    int t = threadIdx.x;
    int v = (t < nb) ? bsums[t] : 0;
    s[t] = v;
    __syncthreads();
    for (int o = 1; o < 512; o <<= 1) {
        int x = 0;
        if (t >= o) x = s[t - o];
        __syncthreads();
        s[t] += x;
        __syncthreads();
    }
    if (t < nb) boffs[t] = s[t] - v;  // exclusive
    if (t == 0) offs[N] = E;
}

// ---------- scan pass 3: per-block exclusive scan + block offset ----------
__global__ __launch_bounds__(256) void scan256(const int* __restrict__ cnt,
                                               const int* __restrict__ boffs,
                                               int* __restrict__ offs, int n) {
    __shared__ int s[256];
    int t = threadIdx.x, g = blockIdx.x * 256 + t;
    int v = (g < n) ? cnt[g] : 0;
    s[t] = v;
    __syncthreads();
    for (int o = 1; o < 256; o <<= 1) {
        int x = 0;
        if (t >= o) x = s[t - o];
        __syncthreads();
        s[t] += x;
        __syncthreads();
    }
    if (g < n) offs[g] = boffs[blockIdx.x] + s[t] - v;
}

// ---------- CSR fill (order within a node nondeterministic; fp32-sum tolerant) ----------
__global__ __launch_bounds__(256) void fill_kernel(const int* __restrict__ src,
                                                   const int* __restrict__ dst,
                                                   int* __restrict__ cur,
                                                   const int* __restrict__ offs,
                                                   int* __restrict__ adj, int E) {
    int e = blockIdx.x * 256 + threadIdx.x;
    if (e < E) {
        int d = dst[e];
        int p = atomicAdd(&cur[d], 1);
        adj[offs[d] + p] = src[e];
    }
}

// ---------- transpose both weights (fp32 in, bf16 out): Wt[n][k] = bf16(W[k][n]) ----------
__global__ __launch_bounds__(256) void transpose_w(const float* __restrict__ W1,
                                                   const float* __restrict__ W2,
                                                   ushort_t* __restrict__ W1t,
                                                   ushort_t* __restrict__ W2t) {
    int idx = blockIdx.x * 256 + threadIdx.x;  // 0..32767
    int sel = idx >> 14;
    int i = idx & 16383;
    int k = i >> 7, nn = i & 127;
    const float* S = sel ? W2 : W1;
    ushort_t* D = sel ? W2t : W1t;
    D[nn * 128 + k] = f2b(S[k * 128 + nn]);
}

// ---------- GEMM: Hout[i][:] = bf16((Xin[i][:] @ W) * dinv[i]) ----------
// MFMA 16x16x32 bf16. A frag: A[m=lane&15][k=q*8+j]; B frag: B[k=q*8+j][n=lane&15];
// D: col=lane&15, row=q*4+r  (learn_hip m89/m91 verified layouts).
__global__ __launch_bounds__(256, 4) void gemm_scale(const ushort_t* __restrict__ Xin,
                                                     const ushort_t* __restrict__ Wt,
                                                     const float* __restrict__ dinv,
                                                     ushort_t* __restrict__ Hout, int n) {
    // W^T staged in LDS, leading dim padded 128->136 (stride 272B -> 2-way bank alias, free)
    __shared__ ushort_t lds[128 * 136];
    int tid = threadIdx.x;
    for (int i = tid; i < 128 * 16; i += 256) {
        int r = i >> 4, c8 = (i & 15) << 3;
        *(uint32x4*)(lds + r * 136 + c8) = *(const uint32x4*)(Wt + r * 128 + c8);
    }
    __syncthreads();
    int lane = tid & 63, wave = tid >> 6;
    int m = lane & 15, q = lane >> 4;
    int row0 = blockIdx.x * 64 + wave * 16;
    int ar = row0 + m;
    if (ar > n - 1) ar = n - 1;  // clamp; garbage rows masked at store
    bf16x8 a[4];
#pragma unroll
    for (int ks = 0; ks < 4; ++ks)
        a[ks] = __builtin_bit_cast(bf16x8,
            *(const uint32x4*)(Xin + (size_t)ar * 128 + ks * 32 + q * 8));
    f32x4 acc[8];
    f32x4 zero = {0.f, 0.f, 0.f, 0.f};
#pragma unroll
    for (int nt = 0; nt < 8; ++nt) acc[nt] = zero;
#pragma unroll
    for (int nt = 0; nt < 8; ++nt) {
#pragma unroll
        for (int ks = 0; ks < 4; ++ks) {
            bf16x8 b = __builtin_bit_cast(bf16x8,
                *(const uint32x4*)(lds + (nt * 16 + m) * 136 + ks * 32 + q * 8));
            acc[nt] = __builtin_amdgcn_mfma_f32_16x16x32_bf16(a[ks], b, acc[nt], 0, 0, 0);
        }
    }
    float dv[4];
#pragma unroll
    for (int r = 0; r < 4; ++r) {
        int gr = row0 + q * 4 + r;
        dv[r] = (gr < n) ? dinv[gr] : 0.f;
    }
#pragma unroll
    for (int nt = 0; nt < 8; ++nt) {
#pragma unroll
        for (int r = 0; r < 4; ++r) {
            int gr = row0 + q * 4 + r;
            if (gr < n)
                Hout[(size_t)gr * 128 + nt * 16 + m] = f2b(acc[nt][r] * dv[r]);
        }
    }
}

// ---------- aggregation: Out[i] = relu(dinv[i]*(sum_{s in N(i)} Hs[s] + Hs[i]) + b) ----------
// one wave per node; lane handles 2 columns (128 cols / 64 lanes); 4-wide edge unroll for MLP
__global__ __launch_bounds__(256, 8) void agg_kernel(const ushort_t* __restrict__ Hs,
                                                     const int* __restrict__ adj,
                                                     const int* __restrict__ offs,
                                                     const float* __restrict__ dinv,
                                                     const float* __restrict__ bias,
                                                     ushort_t* __restrict__ Out, int n) {
    int node = blockIdx.x * 4 + (threadIdx.x >> 6);
    if (node >= n) return;
    int lane = threadIdx.x & 63;
    size_t col = (size_t)lane * 2;
    const int beg = offs[node], end = offs[node + 1];
    uint_t v = *(const uint_t*)(Hs + (size_t)node * 128 + col);  // self-loop term
    float a0 = lo2f(v), a1 = hi2f(v);
    int e = beg;
    for (; e + 4 <= end; e += 4) {
        int s0 = adj[e], s1 = adj[e + 1], s2 = adj[e + 2], s3 = adj[e + 3];
        uint_t w0 = *(const uint_t*)(Hs + (size_t)s0 * 128 + col);
        uint_t w1 = *(const uint_t*)(Hs + (size_t)s1 * 128 + col);
        uint_t w2 = *(const uint_t*)(Hs + (size_t)s2 * 128 + col);
        uint_t w3 = *(const uint_t*)(Hs + (size_t)s3 * 128 + col);
        a0 += lo2f(w0); a1 += hi2f(w0);
        a0 += lo2f(w1); a1 += hi2f(w1);
        a0 += lo2f(w2); a1 += hi2f(w2);
        a0 += lo2f(w3); a1 += hi2f(w3);
    }
    for (; e < end; ++e) {
        int s = adj[e];
        uint_t w = *(const uint_t*)(Hs + (size_t)s * 128 + col);
        a0 += lo2f(w); a1 += hi2f(w);
    }
    float di = dinv[node];
    float o0 = fmaxf(di * a0 + bias[lane * 2 + 0], 0.f);
    float o1 = fmaxf(di * a1 + bias[lane * 2 + 1], 0.f);
    *(uint_t*)(Out + (size_t)node * 128 + col) =
        (uint_t)f2b(o0) | ((uint_t)f2b(o1) << 16);
}

// ---------- pooling + classifier: out[g] = sigmoid(mean_{i in g}(A[i]) . Wc + bc) ----------
__global__ __launch_bounds__(128) void pool_kernel(const ushort_t* __restrict__ A,
                                                   const int* __restrict__ batch,
                                                   const float* __restrict__ Wc,
                                                   const float* __restrict__ bc,
                                                   float* __restrict__ out, int n) {
    int g = blockIdx.x;
    int j = threadIdx.x;
    // batch is sorted: nodes of graph g form a contiguous range [start, stop)
    int lo = 0, hi = n;
    while (lo < hi) { int mid = (lo + hi) >> 1; if (batch[mid] < g) lo = mid + 1; else hi = mid; }
    int start = lo;
    hi = n;
    while (lo < hi) { int mid = (lo + hi) >> 1; if (batch[mid] < g + 1) lo = mid + 1; else hi = mid; }
    int stop = lo;
    float s = 0.f;
    for (int i = start; i < stop; ++i) s += b2f(A[(size_t)i * 128 + j]);
    int cg = stop - start;
    float pooled = s / (float)(cg > 0 ? cg : 1);
    float val = pooled * Wc[j];
    __shared__ float red[128];
    red[j] = val;
    __syncthreads();
    for (int o = 64; o > 0; o >>= 1) {
        if (j < o) red[j] += red[j + o];
        __syncthreads();
    }
    if (j == 0) {
        float z = red[0] + bc[0];
        out[g] = 1.f / (1.f + expf(-z));
    }
}

extern "C" void kernel_launch(void* const* d_in, const int* in_sizes, int n_in,
                              void* d_out, int out_size, void* d_ws, size_t ws_size,
                              hipStream_t stream) {
    const float* X     = (const float*)d_in[0];
    const int* ei      = (const int*)d_in[1];
    const int* batch   = (const int*)d_in[2];
    const float* W1    = (const float*)d_in[3];
    const float* b1    = (const float*)d_in[4];
    const float* W2    = (const float*)d_in[5];
    const float* b2    = (const float*)d_in[6];
    const float* Wc    = (const float*)d_in[7];
    const float* bc    = (const float*)d_in[8];

    const int N = in_sizes[2];
    const int E = in_sizes[1] / 2;
    const int G = out_size;
    const int* srcv = ei;
    const int* dstv = ei + E;
    const int NB = (N + 255) / 256;

    char* p = (char*)d_ws;
    auto alloc = [&](size_t bytes) -> void* {
        void* r = (void*)p;
        p += (bytes + 255) & ~(size_t)255;
        return r;
    };
    int* cnt      = (int*)alloc((size_t)NB * 256 * 4);
    int* cur      = (int*)alloc((size_t)NB * 256 * 4);
    int* offs     = (int*)alloc(((size_t)N + 1) * 4);
    float* dinv   = (float*)alloc((size_t)N * 4);
    int* bsums    = (int*)alloc((size_t)NB * 4);
    int* boffs    = (int*)alloc((size_t)NB * 4);
    int* adj      = (int*)alloc((size_t)E * 4);
    ushort_t* W1t = (ushort_t*)alloc(16384 * 2);
    ushort_t* W2t = (ushort_t*)alloc(16384 * 2);
    ushort_t* Xb  = (ushort_t*)alloc((size_t)N * 128 * 2);
    ushort_t* buf1 = (ushort_t*)alloc((size_t)N * 128 * 2);
    ushort_t* buf2 = (ushort_t*)alloc((size_t)N * 128 * 2);

    hipMemsetAsync(cnt, 0, (size_t)NB * 256 * 4, stream);
    hipMemsetAsync(cur, 0, (size_t)NB * 256 * 4, stream);

    const int EB = (E + 255) / 256;
    count_kernel<<<EB, 256, 0, stream>>>(dstv, cnt, E);
    dinv_kernel<<<NB, 256, 0, stream>>>(cnt, dinv, N);
    reduce256<<<NB, 256, 0, stream>>>(cnt, bsums, N);
    scan_block<<<1, 512, 0, stream>>>(bsums, boffs, NB, offs, N, E);
    scan256<<<NB, 256, 0, stream>>>(cnt, boffs, offs, N);
    fill_kernel<<<EB, 256, 0, stream>>>(srcv, dstv, cur, offs, adj, E);
    transpose_w<<<128, 256, 0, stream>>>(W1, W2, W1t, W2t);

    const int n8 = N * 128 / 8;  // N*128 divisible by 8
    cast_kernel<<<(n8 + 255) / 256, 256, 0, stream>>>(X, Xb, n8);

    const int GB = (N + 63) / 64;
    const int AB = (N + 3) / 4;
    // layer 1
    gemm_scale<<<GB, 256, 0, stream>>>(Xb, W1t, dinv, buf1, N);
    agg_kernel<<<AB, 256, 0, stream>>>(buf1, adj, offs, dinv, b1, buf2, N);
    // layer 2
    gemm_scale<<<GB, 256, 0, stream>>>(buf2, W2t, dinv, buf1, N);
    agg_kernel<<<AB, 256, 0, stream>>>(buf1, adj, offs, dinv, b2, buf2, N);
    // pool + classifier
    pool_kernel<<<G, 128, 0, stream>>>(buf2, batch, Wc, bc, (float*)d_out, N);
}

// Round 3
// 628.813 us; speedup vs baseline: 1.2433x; 1.2433x over previous
//
#include <hip/hip_runtime.h>

typedef unsigned short ushort_t;
typedef unsigned int uint_t;

typedef __bf16 bf16x8 __attribute__((ext_vector_type(8)));
typedef float f32x4 __attribute__((ext_vector_type(4)));
typedef uint_t uint32x4 __attribute__((ext_vector_type(4)));

// ---------- bf16 helpers (RNE fp32->bf16; bit-shift bf16->fp32) ----------
__device__ __forceinline__ float b2f(ushort_t u) {
    union { uint_t ui; float f; } c; c.ui = ((uint_t)u) << 16; return c.f;
}
__device__ __forceinline__ ushort_t f2b(float f) {
    union { float f; uint_t ui; } c; c.f = f;
    uint_t u = c.ui;
    uint_t r = (u + 0x7fffu + ((u >> 16) & 1u)) >> 16;
    return (ushort_t)r;
}
__device__ __forceinline__ float lo2f(uint_t v) {
    union { uint_t u; float f; } c; c.u = v << 16; return c.f;
}
__device__ __forceinline__ float hi2f(uint_t v) {
    union { uint_t u; float f; } c; c.u = v & 0xffff0000u; return c.f;
}

// ---------- combined degree count + per-edge rank (ONE atomic pass) ----------
__global__ __launch_bounds__(256) void count_pos_kernel(const int* __restrict__ dst,
                                                        int* __restrict__ cnt,
                                                        int* __restrict__ pos, int E) {
    int e = blockIdx.x * 256 + threadIdx.x;
    if (e < E) pos[e] = atomicAdd(&cnt[dst[e]], 1);
}

// ---------- dinv = rsqrt(indeg + 1)  (self-loop always present -> deg>0) ----------
__global__ __launch_bounds__(256) void dinv_kernel(const int* __restrict__ cnt,
                                                   float* __restrict__ dinv, int n) {
    int i = blockIdx.x * 256 + threadIdx.x;
    if (i < n) dinv[i] = rsqrtf((float)(cnt[i] + 1));
}

// ---------- scan pass 1: per-block sums ----------
__global__ __launch_bounds__(256) void reduce256(const int* __restrict__ cnt,
                                                 int* __restrict__ bsums, int n) {
    __shared__ int s[256];
    int t = threadIdx.x, g = blockIdx.x * 256 + t;
    s[t] = (g < n) ? cnt[g] : 0;
    __syncthreads();
    for (int o = 128; o > 0; o >>= 1) {
        if (t < o) s[t] += s[t + o];
        __syncthreads();
    }
    if (t == 0) bsums[blockIdx.x] = s[0];
}

// ---------- scan pass 2: exclusive scan of block sums (single block) ----------
__global__ __launch_bounds__(512) void scan_block(const int* __restrict__ bsums,
                                                  int* __restrict__ boffs, int nb,
                                                  int* __restrict__ offs, int N, int E) {
    __shared__ int s[512];
    int t = threadIdx.x;
    int v = (t < nb) ? bsums[t] : 0;
    s[t] = v;
    __syncthreads();
    for (int o = 1; o < 512; o <<= 1) {
        int x = 0;
        if (t >= o) x = s[t - o];
        __syncthreads();
        s[t] += x;
        __syncthreads();
    }
    if (t < nb) boffs[t] = s[t] - v;  // exclusive
    if (t == 0) offs[N] = E;
}

// ---------- scan pass 3: per-block exclusive scan + block offset ----------
__global__ __launch_bounds__(256) void scan256(const int* __restrict__ cnt,
                                               const int* __restrict__ boffs,
                                               int* __restrict__ offs, int n) {
    __shared__ int s[256];
    int t = threadIdx.x, g = blockIdx.x * 256 + t;
    int v = (g < n) ? cnt[g] : 0;
    s[t] = v;
    __syncthreads();
    for (int o = 1; o < 256; o <<= 1) {
        int x = 0;
        if (t >= o) x = s[t - o];
        __syncthreads();
        s[t] += x;
        __syncthreads();
    }
    if (g < n) offs[g] = boffs[blockIdx.x] + s[t] - v;
}

// ---------- CSR fill: plain scatter, NO atomics (rank precomputed) ----------
__global__ __launch_bounds__(256) void scatter_kernel(const int* __restrict__ src,
                                                      const int* __restrict__ dst,
                                                      const int* __restrict__ pos,
                                                      const int* __restrict__ offs,
                                                      int* __restrict__ adj, int E) {
    int e = blockIdx.x * 256 + threadIdx.x;
    if (e < E) adj[offs[dst[e]] + pos[e]] = src[e];
}

// ---------- transpose both weights (fp32 in, bf16 out): Wt[n][k] = bf16(W[k][n]) ----------
__global__ __launch_bounds__(256) void transpose_w(const float* __restrict__ W1,
                                                   const float* __restrict__ W2,
                                                   ushort_t* __restrict__ W1t,
                                                   ushort_t* __restrict__ W2t) {
    int idx = blockIdx.x * 256 + threadIdx.x;  // 0..32767
    int sel = idx >> 14;
    int i = idx & 16383;
    int k = i >> 7, nn = i & 127;
    const float* S = sel ? W2 : W1;
    ushort_t* D = sel ? W2t : W1t;
    D[nn * 128 + k] = f2b(S[k * 128 + nn]);
}

// ---------- GEMM (bf16 A in): Hout[i][:] = bf16((Xin[i][:] @ W) * dinv[i]) ----------
// MFMA 16x16x32 bf16. A frag: A[m=lane&15][k=q*8+j]; B frag: B[k=q*8+j][n=lane&15];
// D: col=lane&15, row=q*4+r  (learn_hip m89/m91 verified layouts).
__global__ __launch_bounds__(256, 4) void gemm_scale(const ushort_t* __restrict__ Xin,
                                                     const ushort_t* __restrict__ Wt,
                                                     const float* __restrict__ dinv,
                                                     ushort_t* __restrict__ Hout, int n) {
    // W^T staged in LDS, leading dim padded 128->136 (stride 272B -> 2-way bank alias, free)
    __shared__ ushort_t lds[128 * 136];
    int tid = threadIdx.x;
    for (int i = tid; i < 128 * 16; i += 256) {
        int r = i >> 4, c8 = (i & 15) << 3;
        *(uint32x4*)(lds + r * 136 + c8) = *(const uint32x4*)(Wt + r * 128 + c8);
    }
    __syncthreads();
    int lane = tid & 63, wave = tid >> 6;
    int m = lane & 15, q = lane >> 4;
    int row0 = blockIdx.x * 64 + wave * 16;
    int ar = row0 + m;
    if (ar > n - 1) ar = n - 1;  // clamp; garbage rows masked at store
    bf16x8 a[4];
#pragma unroll
    for (int ks = 0; ks < 4; ++ks)
        a[ks] = __builtin_bit_cast(bf16x8,
            *(const uint32x4*)(Xin + (size_t)ar * 128 + ks * 32 + q * 8));
    f32x4 acc[8];
    f32x4 zero = {0.f, 0.f, 0.f, 0.f};
#pragma unroll
    for (int nt = 0; nt < 8; ++nt) acc[nt] = zero;
#pragma unroll
    for (int nt = 0; nt < 8; ++nt) {
#pragma unroll
        for (int ks = 0; ks < 4; ++ks) {
            bf16x8 b = __builtin_bit_cast(bf16x8,
                *(const uint32x4*)(lds + (nt * 16 + m) * 136 + ks * 32 + q * 8));
            acc[nt] = __builtin_amdgcn_mfma_f32_16x16x32_bf16(a[ks], b, acc[nt], 0, 0, 0);
        }
    }
    float dv[4];
#pragma unroll
    for (int r = 0; r < 4; ++r) {
        int gr = row0 + q * 4 + r;
        dv[r] = (gr < n) ? dinv[gr] : 0.f;
    }
#pragma unroll
    for (int nt = 0; nt < 8; ++nt) {
#pragma unroll
        for (int r = 0; r < 4; ++r) {
            int gr = row0 + q * 4 + r;
            if (gr < n)
                Hout[(size_t)gr * 128 + nt * 16 + m] = f2b(acc[nt][r] * dv[r]);
        }
    }
}

// ---------- GEMM layer-1 variant: fp32 A input, converts in-register ----------
__global__ __launch_bounds__(256, 4) void gemm_scale_f32(const float* __restrict__ Xf,
                                                         const ushort_t* __restrict__ Wt,
                                                         const float* __restrict__ dinv,
                                                         ushort_t* __restrict__ Hout, int n) {
    __shared__ ushort_t lds[128 * 136];
    int tid = threadIdx.x;
    for (int i = tid; i < 128 * 16; i += 256) {
        int r = i >> 4, c8 = (i & 15) << 3;
        *(uint32x4*)(lds + r * 136 + c8) = *(const uint32x4*)(Wt + r * 128 + c8);
    }
    __syncthreads();
    int lane = tid & 63, wave = tid >> 6;
    int m = lane & 15, q = lane >> 4;
    int row0 = blockIdx.x * 64 + wave * 16;
    int ar = row0 + m;
    if (ar > n - 1) ar = n - 1;
    bf16x8 a[4];
#pragma unroll
    for (int ks = 0; ks < 4; ++ks) {
        const float* p = Xf + (size_t)ar * 128 + ks * 32 + q * 8;
        f32x4 lo = *(const f32x4*)p;
        f32x4 hi = *(const f32x4*)(p + 4);
        ushort_t t[8];
        t[0] = f2b(lo[0]); t[1] = f2b(lo[1]); t[2] = f2b(lo[2]); t[3] = f2b(lo[3]);
        t[4] = f2b(hi[0]); t[5] = f2b(hi[1]); t[6] = f2b(hi[2]); t[7] = f2b(hi[3]);
        a[ks] = __builtin_bit_cast(bf16x8, *(uint32x4*)t);
    }
    f32x4 acc[8];
    f32x4 zero = {0.f, 0.f, 0.f, 0.f};
#pragma unroll
    for (int nt = 0; nt < 8; ++nt) acc[nt] = zero;
#pragma unroll
    for (int nt = 0; nt < 8; ++nt) {
#pragma unroll
        for (int ks = 0; ks < 4; ++ks) {
            bf16x8 b = __builtin_bit_cast(bf16x8,
                *(const uint32x4*)(lds + (nt * 16 + m) * 136 + ks * 32 + q * 8));
            acc[nt] = __builtin_amdgcn_mfma_f32_16x16x32_bf16(a[ks], b, acc[nt], 0, 0, 0);
        }
    }
    float dv[4];
#pragma unroll
    for (int r = 0; r < 4; ++r) {
        int gr = row0 + q * 4 + r;
        dv[r] = (gr < n) ? dinv[gr] : 0.f;
    }
#pragma unroll
    for (int nt = 0; nt < 8; ++nt) {
#pragma unroll
        for (int r = 0; r < 4; ++r) {
            int gr = row0 + q * 4 + r;
            if (gr < n)
                Hout[(size_t)gr * 128 + nt * 16 + m] = f2b(acc[nt][r] * dv[r]);
        }
    }
}

// ---------- aggregation: Out[i] = relu(dinv[i]*(sum_{s in N(i)} Hs[s] + Hs[i]) + b) ----------
// one wave per node; lane handles 2 cols (dword); 8-wide edge unroll for MLP
__global__ __launch_bounds__(256, 8) void agg_kernel(const ushort_t* __restrict__ Hs,
                                                     const int* __restrict__ adj,
                                                     const int* __restrict__ offs,
                                                     const float* __restrict__ dinv,
                                                     const float* __restrict__ bias,
                                                     ushort_t* __restrict__ Out, int n) {
    int node = blockIdx.x * 4 + (threadIdx.x >> 6);
    if (node >= n) return;
    int lane = threadIdx.x & 63;
    size_t col = (size_t)lane * 2;
    const int beg = offs[node], end = offs[node + 1];
    uint_t v = *(const uint_t*)(Hs + (size_t)node * 128 + col);  // self-loop term
    float a0 = lo2f(v), a1 = hi2f(v);
    int e = beg;
    for (; e + 8 <= end; e += 8) {
        int s0 = adj[e + 0], s1 = adj[e + 1], s2 = adj[e + 2], s3 = adj[e + 3];
        int s4 = adj[e + 4], s5 = adj[e + 5], s6 = adj[e + 6], s7 = adj[e + 7];
        uint_t w0 = *(const uint_t*)(Hs + (size_t)s0 * 128 + col);
        uint_t w1 = *(const uint_t*)(Hs + (size_t)s1 * 128 + col);
        uint_t w2 = *(const uint_t*)(Hs + (size_t)s2 * 128 + col);
        uint_t w3 = *(const uint_t*)(Hs + (size_t)s3 * 128 + col);
        uint_t w4 = *(const uint_t*)(Hs + (size_t)s4 * 128 + col);
        uint_t w5 = *(const uint_t*)(Hs + (size_t)s5 * 128 + col);
        uint_t w6 = *(const uint_t*)(Hs + (size_t)s6 * 128 + col);
        uint_t w7 = *(const uint_t*)(Hs + (size_t)s7 * 128 + col);
        a0 += lo2f(w0); a1 += hi2f(w0);
        a0 += lo2f(w1); a1 += hi2f(w1);
        a0 += lo2f(w2); a1 += hi2f(w2);
        a0 += lo2f(w3); a1 += hi2f(w3);
        a0 += lo2f(w4); a1 += hi2f(w4);
        a0 += lo2f(w5); a1 += hi2f(w5);
        a0 += lo2f(w6); a1 += hi2f(w6);
        a0 += lo2f(w7); a1 += hi2f(w7);
    }
    for (; e < end; ++e) {
        int s = adj[e];
        uint_t w = *(const uint_t*)(Hs + (size_t)s * 128 + col);
        a0 += lo2f(w); a1 += hi2f(w);
    }
    float di = dinv[node];
    float o0 = fmaxf(di * a0 + bias[lane * 2 + 0], 0.f);
    float o1 = fmaxf(di * a1 + bias[lane * 2 + 1], 0.f);
    *(uint_t*)(Out + (size_t)node * 128 + col) =
        (uint_t)f2b(o0) | ((uint_t)f2b(o1) << 16);
}

// ---------- pooling + classifier: out[g] = sigmoid(mean_{i in g}(A[i]) . Wc + bc) ----------
__global__ __launch_bounds__(128) void pool_kernel(const ushort_t* __restrict__ A,
                                                   const int* __restrict__ batch,
                                                   const float* __restrict__ Wc,
                                                   const float* __restrict__ bc,
                                                   float* __restrict__ out, int n) {
    int g = blockIdx.x;
    int j = threadIdx.x;
    // batch is sorted: nodes of graph g form a contiguous range [start, stop)
    int lo = 0, hi = n;
    while (lo < hi) { int mid = (lo + hi) >> 1; if (batch[mid] < g) lo = mid + 1; else hi = mid; }
    int start = lo;
    hi = n;
    while (lo < hi) { int mid = (lo + hi) >> 1; if (batch[mid] < g + 1) lo = mid + 1; else hi = mid; }
    int stop = lo;
    float s = 0.f;
    for (int i = start; i < stop; ++i) s += b2f(A[(size_t)i * 128 + j]);
    int cg = stop - start;
    float pooled = s / (float)(cg > 0 ? cg : 1);
    float val = pooled * Wc[j];
    __shared__ float red[128];
    red[j] = val;
    __syncthreads();
    for (int o = 64; o > 0; o >>= 1) {
        if (j < o) red[j] += red[j + o];
        __syncthreads();
    }
    if (j == 0) {
        float z = red[0] + bc[0];
        out[g] = 1.f / (1.f + expf(-z));
    }
}

extern "C" void kernel_launch(void* const* d_in, const int* in_sizes, int n_in,
                              void* d_out, int out_size, void* d_ws, size_t ws_size,
                              hipStream_t stream) {
    const float* X     = (const float*)d_in[0];
    const int* ei      = (const int*)d_in[1];
    const int* batch   = (const int*)d_in[2];
    const float* W1    = (const float*)d_in[3];
    const float* b1    = (const float*)d_in[4];
    const float* W2    = (const float*)d_in[5];
    const float* b2    = (const float*)d_in[6];
    const float* Wc    = (const float*)d_in[7];
    const float* bc    = (const float*)d_in[8];

    const int N = in_sizes[2];
    const int E = in_sizes[1] / 2;
    const int G = out_size;
    const int* srcv = ei;
    const int* dstv = ei + E;
    const int NB = (N + 255) / 256;

    char* p = (char*)d_ws;
    auto alloc = [&](size_t bytes) -> void* {
        void* r = (void*)p;
        p += (bytes + 255) & ~(size_t)255;
        return r;
    };
    int* cnt      = (int*)alloc((size_t)NB * 256 * 4);
    int* pos      = (int*)alloc((size_t)E * 4);
    int* offs     = (int*)alloc(((size_t)N + 1) * 4);
    float* dinv   = (float*)alloc((size_t)N * 4);
    int* bsums    = (int*)alloc((size_t)NB * 4);
    int* boffs    = (int*)alloc((size_t)NB * 4);
    int* adj      = (int*)alloc((size_t)E * 4);
    ushort_t* W1t = (ushort_t*)alloc(16384 * 2);
    ushort_t* W2t = (ushort_t*)alloc(16384 * 2);
    ushort_t* buf1 = (ushort_t*)alloc((size_t)N * 128 * 2);
    ushort_t* buf2 = (ushort_t*)alloc((size_t)N * 128 * 2);

    hipMemsetAsync(cnt, 0, (size_t)NB * 256 * 4, stream);

    const int EB = (E + 255) / 256;
    count_pos_kernel<<<EB, 256, 0, stream>>>(dstv, cnt, pos, E);
    dinv_kernel<<<NB, 256, 0, stream>>>(cnt, dinv, N);
    reduce256<<<NB, 256, 0, stream>>>(cnt, bsums, N);
    scan_block<<<1, 512, 0, stream>>>(bsums, boffs, NB, offs, N, E);
    scan256<<<NB, 256, 0, stream>>>(cnt, boffs, offs, N);
    scatter_kernel<<<EB, 256, 0, stream>>>(srcv, dstv, pos, offs, adj, E);
    transpose_w<<<128, 256, 0, stream>>>(W1, W2, W1t, W2t);

    const int GB = (N + 63) / 64;
    const int AB = (N + 3) / 4;
    // layer 1 (cast fused into GEMM)
    gemm_scale_f32<<<GB, 256, 0, stream>>>(X, W1t, dinv, buf1, N);
    agg_kernel<<<AB, 256, 0, stream>>>(buf1, adj, offs, dinv, b1, buf2, N);
    // layer 2
    gemm_scale<<<GB, 256, 0, stream>>>(buf2, W2t, dinv, buf1, N);
    agg_kernel<<<AB, 256, 0, stream>>>(buf1, adj, offs, dinv, b2, buf2, N);
    // pool + classifier
    pool_kernel<<<G, 128, 0, stream>>>(buf2, batch, Wc, bc, (float*)d_out, N);
}

// Round 4
// 546.687 us; speedup vs baseline: 1.4300x; 1.1502x over previous
//
#include <hip/hip_runtime.h>

typedef unsigned short ushort_t;
typedef unsigned int uint_t;

typedef __bf16 bf16x8 __attribute__((ext_vector_type(8)));
typedef float f32x4 __attribute__((ext_vector_type(4)));
typedef uint_t uint32x4 __attribute__((ext_vector_type(4)));

#define EPB 4096     // edges per build block
#define NSH 7        // bucket = dst >> NSH  (128 nodes/bucket)
#define CAP 6144     // LDS edge-staging capacity in p4 (mean bucket ~4096)

// ---------- bf16 helpers (RNE fp32->bf16; bit-shift bf16->fp32) ----------
__device__ __forceinline__ float b2f(ushort_t u) {
    union { uint_t ui; float f; } c; c.ui = ((uint_t)u) << 16; return c.f;
}
__device__ __forceinline__ ushort_t f2b(float f) {
    union { float f; uint_t ui; } c; c.f = f;
    uint_t u = c.ui;
    uint_t r = (u + 0x7fffu + ((u >> 16) & 1u)) >> 16;
    return (ushort_t)r;
}
__device__ __forceinline__ float lo2f(uint_t v) {
    union { uint_t u; float f; } c; c.u = v << 16; return c.f;
}
__device__ __forceinline__ float hi2f(uint_t v) {
    union { uint_t u; float f; } c; c.u = v & 0xffff0000u; return c.f;
}

// ---------- P1: per-chunk bucket histogram (LDS atomics only) ----------
__global__ __launch_bounds__(256) void p1_hist(const int* __restrict__ dst,
                                               int* __restrict__ H,
                                               int E, int NBLK, int B) {
    __shared__ int hist[1024];
    int t = threadIdx.x, c = blockIdx.x;
    for (int b = t; b < 1024; b += 256) hist[b] = 0;
    __syncthreads();
    int base = c * EPB;
    int lim = min(E - base, EPB);
    for (int i = t; i < lim; i += 256)
        atomicAdd(&hist[dst[base + i] >> NSH], 1);
    __syncthreads();
    for (int b = t; b < B; b += 256) H[b * NBLK + c] = hist[b];
}

// ---------- scan pass 1: per-256-chunk sums ----------
__global__ __launch_bounds__(256) void reduce256(const int* __restrict__ in,
                                                 int* __restrict__ bsums, int n) {
    __shared__ int s[256];
    int t = threadIdx.x, g = blockIdx.x * 256 + t;
    s[t] = (g < n) ? in[g] : 0;
    __syncthreads();
    for (int o = 128; o > 0; o >>= 1) {
        if (t < o) s[t] += s[t + o];
        __syncthreads();
    }
    if (t == 0) bsums[blockIdx.x] = s[0];
}

// ---------- scan pass 2: single-block exclusive scan (n <= 512) ----------
__global__ __launch_bounds__(512) void scan_small(const int* __restrict__ in,
                                                  int* __restrict__ outEx, int n) {
    __shared__ int s[512];
    int t = threadIdx.x;
    int v = (t < n) ? in[t] : 0;
    s[t] = v;
    __syncthreads();
    for (int o = 1; o < 512; o <<= 1) {
        int x = 0;
        if (t >= o) x = s[t - o];
        __syncthreads();
        s[t] += x;
        __syncthreads();
    }
    if (t < n) outEx[t] = s[t] - v;
}

// ---------- scan pass 3: per-chunk exclusive scan + chunk offset ----------
__global__ __launch_bounds__(256) void scan256ex(const int* __restrict__ in,
                                                 const int* __restrict__ boffs,
                                                 int* __restrict__ outEx, int n) {
    __shared__ int s[256];
    int t = threadIdx.x, g = blockIdx.x * 256 + t;
    int v = (g < n) ? in[g] : 0;
    s[t] = v;
    __syncthreads();
    for (int o = 1; o < 256; o <<= 1) {
        int x = 0;
        if (t >= o) x = s[t - o];
        __syncthreads();
        s[t] += x;
        __syncthreads();
    }
    if (g < n) outEx[g] = boffs[blockIdx.x] + s[t] - v;
}

// ---------- P3: partition scatter (LDS rank; streaming global writes) ----------
__global__ __launch_bounds__(256) void p3_scatter(const int* __restrict__ src,
                                                  const int* __restrict__ dst,
                                                  const int* __restrict__ Hex,
                                                  uint_t* __restrict__ packed,
                                                  int E, int NBLK, int B) {
    __shared__ int offsL[1024];
    __shared__ int cur[1024];
    int t = threadIdx.x, c = blockIdx.x;
    for (int b = t; b < B; b += 256) {
        offsL[b] = Hex[b * NBLK + c];
        cur[b] = 0;
    }
    __syncthreads();
    int base = c * EPB;
    int lim = min(E - base, EPB);
    for (int i = t; i < lim; i += 256) {
        int d = dst[base + i];
        int s = src[base + i];
        int b = d >> NSH;
        int r = atomicAdd(&cur[b], 1);
        packed[offsL[b] + r] = ((uint_t)s << NSH) | (uint_t)(d & 127);
    }
}

// ---------- P4: per-bucket CSR build + offs + dinv (LDS only) ----------
__global__ __launch_bounds__(256) void p4_csr(const uint_t* __restrict__ packed,
                                              const int* __restrict__ Hex,
                                              int* __restrict__ adj,
                                              int* __restrict__ offs,
                                              float* __restrict__ dinv,
                                              int E, int N, int NBLK, int B) {
    __shared__ int cnt[128], loc[128], cur[128];
    __shared__ uint_t ebuf[CAP];
    int t = threadIdx.x, b = blockIdx.x;
    int bs = Hex[b * NBLK];
    int be = (b + 1 < B) ? Hex[(b + 1) * NBLK] : E;
    if (t < 128) cnt[t] = 0;
    __syncthreads();
    int m = be - bs;
    for (int i = t; i < m; i += 256) {
        uint_t p = packed[bs + i];
        if (i < CAP) ebuf[i] = p;
        atomicAdd(&cnt[p & 127], 1);
    }
    __syncthreads();
    if (t < 128) loc[t] = cnt[t];
    __syncthreads();
    for (int o = 1; o < 128; o <<= 1) {
        int x = 0;
        if (t < 128 && t >= o) x = loc[t - o];
        __syncthreads();
        if (t < 128) loc[t] += x;
        __syncthreads();
    }
    if (t < 128) {
        int ex = loc[t] - cnt[t];   // exclusive within bucket
        int node = b * 128 + t;
        if (node < N) {
            offs[node] = bs + ex;
            dinv[node] = rsqrtf((float)(cnt[t] + 1));
        }
        loc[t] = ex;
        cur[t] = 0;
    }
    if (b == B - 1 && t == 0) offs[N] = E;
    __syncthreads();
    for (int i = t; i < m; i += 256) {
        uint_t p = (i < CAP) ? ebuf[i] : packed[bs + i];
        int l = p & 127;
        int r = atomicAdd(&cur[l], 1);
        adj[bs + loc[l] + r] = (int)(p >> NSH);
    }
}

// ---------- transpose both weights (fp32 in, bf16 out): Wt[n][k] = bf16(W[k][n]) ----------
__global__ __launch_bounds__(256) void transpose_w(const float* __restrict__ W1,
                                                   const float* __restrict__ W2,
                                                   ushort_t* __restrict__ W1t,
                                                   ushort_t* __restrict__ W2t) {
    int idx = blockIdx.x * 256 + threadIdx.x;  // 0..32767
    int sel = idx >> 14;
    int i = idx & 16383;
    int k = i >> 7, nn = i & 127;
    const float* S = sel ? W2 : W1;
    ushort_t* D = sel ? W2t : W1t;
    D[nn * 128 + k] = f2b(S[k * 128 + nn]);
}

// ---------- GEMM (bf16 A in): Hout[i][:] = bf16((Xin[i][:] @ W) * dinv[i]) ----------
// MFMA 16x16x32 bf16. A frag: A[m=lane&15][k=q*8+j]; B frag: B[k=q*8+j][n=lane&15];
// D: col=lane&15, row=q*4+r  (learn_hip m89/m91 verified layouts).
__global__ __launch_bounds__(256, 4) void gemm_scale(const ushort_t* __restrict__ Xin,
                                                     const ushort_t* __restrict__ Wt,
                                                     const float* __restrict__ dinv,
                                                     ushort_t* __restrict__ Hout, int n) {
    __shared__ ushort_t lds[128 * 136];
    int tid = threadIdx.x;
    for (int i = tid; i < 128 * 16; i += 256) {
        int r = i >> 4, c8 = (i & 15) << 3;
        *(uint32x4*)(lds + r * 136 + c8) = *(const uint32x4*)(Wt + r * 128 + c8);
    }
    __syncthreads();
    int lane = tid & 63, wave = tid >> 6;
    int m = lane & 15, q = lane >> 4;
    int row0 = blockIdx.x * 64 + wave * 16;
    int ar = row0 + m;
    if (ar > n - 1) ar = n - 1;  // clamp; garbage rows masked at store
    bf16x8 a[4];
#pragma unroll
    for (int ks = 0; ks < 4; ++ks)
        a[ks] = __builtin_bit_cast(bf16x8,
            *(const uint32x4*)(Xin + (size_t)ar * 128 + ks * 32 + q * 8));
    f32x4 acc[8];
    f32x4 zero = {0.f, 0.f, 0.f, 0.f};
#pragma unroll
    for (int nt = 0; nt < 8; ++nt) acc[nt] = zero;
#pragma unroll
    for (int nt = 0; nt < 8; ++nt) {
#pragma unroll
        for (int ks = 0; ks < 4; ++ks) {
            bf16x8 b = __builtin_bit_cast(bf16x8,
                *(const uint32x4*)(lds + (nt * 16 + m) * 136 + ks * 32 + q * 8));
            acc[nt] = __builtin_amdgcn_mfma_f32_16x16x32_bf16(a[ks], b, acc[nt], 0, 0, 0);
        }
    }
    float dv[4];
#pragma unroll
    for (int r = 0; r < 4; ++r) {
        int gr = row0 + q * 4 + r;
        dv[r] = (gr < n) ? dinv[gr] : 0.f;
    }
#pragma unroll
    for (int nt = 0; nt < 8; ++nt) {
#pragma unroll
        for (int r = 0; r < 4; ++r) {
            int gr = row0 + q * 4 + r;
            if (gr < n)
                Hout[(size_t)gr * 128 + nt * 16 + m] = f2b(acc[nt][r] * dv[r]);
        }
    }
}

// ---------- GEMM layer-1 variant: fp32 A input, converts in-register ----------
__global__ __launch_bounds__(256, 4) void gemm_scale_f32(const float* __restrict__ Xf,
                                                         const ushort_t* __restrict__ Wt,
                                                         const float* __restrict__ dinv,
                                                         ushort_t* __restrict__ Hout, int n) {
    __shared__ ushort_t lds[128 * 136];
    int tid = threadIdx.x;
    for (int i = tid; i < 128 * 16; i += 256) {
        int r = i >> 4, c8 = (i & 15) << 3;
        *(uint32x4*)(lds + r * 136 + c8) = *(const uint32x4*)(Wt + r * 128 + c8);
    }
    __syncthreads();
    int lane = tid & 63, wave = tid >> 6;
    int m = lane & 15, q = lane >> 4;
    int row0 = blockIdx.x * 64 + wave * 16;
    int ar = row0 + m;
    if (ar > n - 1) ar = n - 1;
    bf16x8 a[4];
#pragma unroll
    for (int ks = 0; ks < 4; ++ks) {
        const float* p = Xf + (size_t)ar * 128 + ks * 32 + q * 8;
        f32x4 lo = *(const f32x4*)p;
        f32x4 hi = *(const f32x4*)(p + 4);
        ushort_t t[8];
        t[0] = f2b(lo[0]); t[1] = f2b(lo[1]); t[2] = f2b(lo[2]); t[3] = f2b(lo[3]);
        t[4] = f2b(hi[0]); t[5] = f2b(hi[1]); t[6] = f2b(hi[2]); t[7] = f2b(hi[3]);
        a[ks] = __builtin_bit_cast(bf16x8, *(uint32x4*)t);
    }
    f32x4 acc[8];
    f32x4 zero = {0.f, 0.f, 0.f, 0.f};
#pragma unroll
    for (int nt = 0; nt < 8; ++nt) acc[nt] = zero;
#pragma unroll
    for (int nt = 0; nt < 8; ++nt) {
#pragma unroll
        for (int ks = 0; ks < 4; ++ks) {
            bf16x8 b = __builtin_bit_cast(bf16x8,
                *(const uint32x4*)(lds + (nt * 16 + m) * 136 + ks * 32 + q * 8));
            acc[nt] = __builtin_amdgcn_mfma_f32_16x16x32_bf16(a[ks], b, acc[nt], 0, 0, 0);
        }
    }
    float dv[4];
#pragma unroll
    for (int r = 0; r < 4; ++r) {
        int gr = row0 + q * 4 + r;
        dv[r] = (gr < n) ? dinv[gr] : 0.f;
    }
#pragma unroll
    for (int nt = 0; nt < 8; ++nt) {
#pragma unroll
        for (int r = 0; r < 4; ++r) {
            int gr = row0 + q * 4 + r;
            if (gr < n)
                Hout[(size_t)gr * 128 + nt * 16 + m] = f2b(acc[nt][r] * dv[r]);
        }
    }
}

// ---------- aggregation: Out[i] = relu(dinv[i]*(sum_{s in N(i)} Hs[s] + Hs[i]) + b) ----------
// one wave per node; lane handles 2 cols (dword); 8-wide edge unroll for MLP
__global__ __launch_bounds__(256, 8) void agg_kernel(const ushort_t* __restrict__ Hs,
                                                     const int* __restrict__ adj,
                                                     const int* __restrict__ offs,
                                                     const float* __restrict__ dinv,
                                                     const float* __restrict__ bias,
                                                     ushort_t* __restrict__ Out, int n) {
    int node = blockIdx.x * 4 + (threadIdx.x >> 6);
    if (node >= n) return;
    int lane = threadIdx.x & 63;
    size_t col = (size_t)lane * 2;
    const int beg = offs[node], end = offs[node + 1];
    uint_t v = *(const uint_t*)(Hs + (size_t)node * 128 + col);  // self-loop term
    float a0 = lo2f(v), a1 = hi2f(v);
    int e = beg;
    for (; e + 8 <= end; e += 8) {
        int s0 = adj[e + 0], s1 = adj[e + 1], s2 = adj[e + 2], s3 = adj[e + 3];
        int s4 = adj[e + 4], s5 = adj[e + 5], s6 = adj[e + 6], s7 = adj[e + 7];
        uint_t w0 = *(const uint_t*)(Hs + (size_t)s0 * 128 + col);
        uint_t w1 = *(const uint_t*)(Hs + (size_t)s1 * 128 + col);
        uint_t w2 = *(const uint_t*)(Hs + (size_t)s2 * 128 + col);
        uint_t w3 = *(const uint_t*)(Hs + (size_t)s3 * 128 + col);
        uint_t w4 = *(const uint_t*)(Hs + (size_t)s4 * 128 + col);
        uint_t w5 = *(const uint_t*)(Hs + (size_t)s5 * 128 + col);
        uint_t w6 = *(const uint_t*)(Hs + (size_t)s6 * 128 + col);
        uint_t w7 = *(const uint_t*)(Hs + (size_t)s7 * 128 + col);
        a0 += lo2f(w0); a1 += hi2f(w0);
        a0 += lo2f(w1); a1 += hi2f(w1);
        a0 += lo2f(w2); a1 += hi2f(w2);
        a0 += lo2f(w3); a1 += hi2f(w3);
        a0 += lo2f(w4); a1 += hi2f(w4);
        a0 += lo2f(w5); a1 += hi2f(w5);
        a0 += lo2f(w6); a1 += hi2f(w6);
        a0 += lo2f(w7); a1 += hi2f(w7);
    }
    for (; e < end; ++e) {
        int s = adj[e];
        uint_t w = *(const uint_t*)(Hs + (size_t)s * 128 + col);
        a0 += lo2f(w); a1 += hi2f(w);
    }
    float di = dinv[node];
    float o0 = fmaxf(di * a0 + bias[lane * 2 + 0], 0.f);
    float o1 = fmaxf(di * a1 + bias[lane * 2 + 1], 0.f);
    *(uint_t*)(Out + (size_t)node * 128 + col) =
        (uint_t)f2b(o0) | ((uint_t)f2b(o1) << 16);
}

// ---------- pooling + classifier: out[g] = sigmoid(mean_{i in g}(A[i]) . Wc + bc) ----------
__global__ __launch_bounds__(128) void pool_kernel(const ushort_t* __restrict__ A,
                                                   const int* __restrict__ batch,
                                                   const float* __restrict__ Wc,
                                                   const float* __restrict__ bc,
                                                   float* __restrict__ out, int n) {
    int g = blockIdx.x;
    int j = threadIdx.x;
    int lo = 0, hi = n;
    while (lo < hi) { int mid = (lo + hi) >> 1; if (batch[mid] < g) lo = mid + 1; else hi = mid; }
    int start = lo;
    hi = n;
    while (lo < hi) { int mid = (lo + hi) >> 1; if (batch[mid] < g + 1) lo = mid + 1; else hi = mid; }
    int stop = lo;
    float s = 0.f;
    for (int i = start; i < stop; ++i) s += b2f(A[(size_t)i * 128 + j]);
    int cg = stop - start;
    float pooled = s / (float)(cg > 0 ? cg : 1);
    float val = pooled * Wc[j];
    __shared__ float red[128];
    red[j] = val;
    __syncthreads();
    for (int o = 64; o > 0; o >>= 1) {
        if (j < o) red[j] += red[j + o];
        __syncthreads();
    }
    if (j == 0) {
        float z = red[0] + bc[0];
        out[g] = 1.f / (1.f + expf(-z));
    }
}

extern "C" void kernel_launch(void* const* d_in, const int* in_sizes, int n_in,
                              void* d_out, int out_size, void* d_ws, size_t ws_size,
                              hipStream_t stream) {
    const float* X     = (const float*)d_in[0];
    const int* ei      = (const int*)d_in[1];
    const int* batch   = (const int*)d_in[2];
    const float* W1    = (const float*)d_in[3];
    const float* b1    = (const float*)d_in[4];
    const float* W2    = (const float*)d_in[5];
    const float* b2    = (const float*)d_in[6];
    const float* Wc    = (const float*)d_in[7];
    const float* bc    = (const float*)d_in[8];

    const int N = in_sizes[2];
    const int E = in_sizes[1] / 2;
    const int G = out_size;
    const int* srcv = ei;
    const int* dstv = ei + E;

    const int NBLK = (E + EPB - 1) / EPB;      // edge chunks (782)
    const int B    = (N + 127) >> NSH;         // node buckets (782)
    const int n0   = B * NBLK;                 // histogram matrix size
    const int g1   = (n0 + 255) / 256;
    const int g2   = (g1 + 255) / 256;

    char* p = (char*)d_ws;
    auto alloc = [&](size_t bytes) -> void* {
        void* r = (void*)p;
        p += (bytes + 255) & ~(size_t)255;
        return r;
    };
    int* H        = (int*)alloc((size_t)n0 * 4);
    int* Hex      = (int*)alloc((size_t)n0 * 4);
    int* S1       = (int*)alloc((size_t)g1 * 4);
    int* S1ex     = (int*)alloc((size_t)g1 * 4);
    int* S2       = (int*)alloc((size_t)g2 * 4);
    int* S2ex     = (int*)alloc((size_t)g2 * 4);
    uint_t* packed = (uint_t*)alloc((size_t)E * 4);
    int* adj      = (int*)alloc((size_t)E * 4);
    int* offs     = (int*)alloc(((size_t)N + 1) * 4);
    float* dinv   = (float*)alloc((size_t)N * 4);
    ushort_t* W1t = (ushort_t*)alloc(16384 * 2);
    ushort_t* W2t = (ushort_t*)alloc(16384 * 2);
    ushort_t* buf1 = (ushort_t*)alloc((size_t)N * 128 * 2);
    ushort_t* buf2 = (ushort_t*)alloc((size_t)N * 128 * 2);

    // ---- CSR build (no global atomics) ----
    p1_hist<<<NBLK, 256, 0, stream>>>(dstv, H, E, NBLK, B);
    reduce256<<<g1, 256, 0, stream>>>(H, S1, n0);
    reduce256<<<g2, 256, 0, stream>>>(S1, S2, g1);
    scan_small<<<1, 512, 0, stream>>>(S2, S2ex, g2);
    scan256ex<<<g2, 256, 0, stream>>>(S1, S2ex, S1ex, g1);
    scan256ex<<<g1, 256, 0, stream>>>(H, S1ex, Hex, n0);
    p3_scatter<<<NBLK, 256, 0, stream>>>(srcv, dstv, Hex, packed, E, NBLK, B);
    p4_csr<<<B, 256, 0, stream>>>(packed, Hex, adj, offs, dinv, E, N, NBLK, B);

    transpose_w<<<128, 256, 0, stream>>>(W1, W2, W1t, W2t);

    const int GB = (N + 63) / 64;
    const int AB = (N + 3) / 4;
    // layer 1 (cast fused into GEMM)
    gemm_scale_f32<<<GB, 256, 0, stream>>>(X, W1t, dinv, buf1, N);
    agg_kernel<<<AB, 256, 0, stream>>>(buf1, adj, offs, dinv, b1, buf2, N);
    // layer 2
    gemm_scale<<<GB, 256, 0, stream>>>(buf2, W2t, dinv, buf1, N);
    agg_kernel<<<AB, 256, 0, stream>>>(buf1, adj, offs, dinv, b2, buf2, N);
    // pool + classifier
    pool_kernel<<<G, 128, 0, stream>>>(buf2, batch, Wc, bc, (float*)d_out, N);
}